// Round 4
// baseline (107.045 us; speedup 1.0000x reference)
//
#include <hip/hip_runtime.h>
#include <math.h>

// Problem constants (reference: K=256, Q=64, T=500001 -> n = 500000)
// KEY ALGEBRA: all inputs to relu are > 0 (softplus weights, squared u2,
// nonneg var), so relu is the identity and the K=256 MLP collapses:
//   sigma2(t) = c0 + sum_e u2_full[t+e] * vr[e]
// with vr[e] = sum_k softplus(raw_beta)[k] * softplus(raw_w)[k][63-e]
//      c0    = softplus(raw_beta0) + sum_k beta[k]*softplus(raw_w0)[k] + 1e-8
// Pure fp32 (MORE accurate than the previous bf16 MFMA version).
#define K_ 256
#define Q_ 64
#define NT 500000
#define TPB 1024                              // t per k_main block (4 per thread)
#define NBLK_F 489                            // u2 blocks, 1024 elems each
#define GRID_MAIN 489                         // ceil(500000/1024)

// Workspace layout (float offsets):
//  [WS_C0]               c0 (see above)
//  [WS_U2 .. +500064)    u2_full fp32: [0..63] var-init, [64+i] = u2[i]
//  [WS_V  .. +64)        vr[e] (reversed collapsed weight vector)
//  [WS_PART/2 .. +512)   per-block sum(u2), sum(u2^2) partials
//  [WS_OUT .. +512)      per-block NLL partials (summed by k_final)
#define WS_C0    2
#define WS_U2    4
#define WS_V     (WS_U2 + Q_ + NT)
#define WS_PART  (WS_V + Q_)
#define WS_PART2 (WS_PART + 512)
#define WS_OUT   (WS_PART2 + 512)

typedef __attribute__((ext_vector_type(4))) float f32x4;

__device__ __forceinline__ float softplusf(float x) {
    return (x > 20.f) ? x : log1pf(__expf(x));
}

// Kernel A: blocks [0,NBLK_F) compute u2 fp32 (float4-vectorized) + per-block
// sum(u2)/sum(u2^2) partials. Block NBLK_F contracts v = W^T beta and c0.
__global__ void k_front(const float* __restrict__ r,
                        const float* __restrict__ a0p,
                        const float* __restrict__ a1p,
                        const float* __restrict__ raw_beta0,
                        const float* __restrict__ raw_beta,
                        const float* __restrict__ raw_w0,
                        const float* __restrict__ raw_w,
                        float* __restrict__ ws) {
    __shared__ float red[8];
    __shared__ float sbeta[K_];
    __shared__ float vpart[4][Q_];
    __shared__ float cred[4];
    int tid = threadIdx.x;

    if (blockIdx.x < NBLK_F) {
        int i0 = 4 * (blockIdx.x * 256 + tid);
        float a0 = a0p[0], a1 = a1p[0];
        float v = 0.f, v2 = 0.f;
        if (i0 + 7 <= NT) {                       // r valid to index NT
            f32x4 ra = *(const f32x4*)(r + i0);
            f32x4 rb = *(const f32x4*)(r + i0 + 4);
            float u0 = ra[1] - a0 - a1 * ra[0];
            float u1 = ra[2] - a0 - a1 * ra[1];
            float u2 = ra[3] - a0 - a1 * ra[2];
            float u3 = rb[0] - a0 - a1 * ra[3];
            f32x4 q; q[0] = u0*u0; q[1] = u1*u1; q[2] = u2*u2; q[3] = u3*u3;
            *(f32x4*)(ws + WS_U2 + Q_ + i0) = q;  // aligned (i0 % 4 == 0)
            v  = (q[0] + q[1]) + (q[2] + q[3]);
            v2 = (q[0]*q[0] + q[1]*q[1]) + (q[2]*q[2] + q[3]*q[3]);
        } else {
            #pragma unroll
            for (int j = 0; j < 4; ++j) {
                int i = i0 + j;
                if (i < NT) {
                    float u = r[i + 1] - a0 - a1 * r[i];
                    float q = u * u;
                    ws[WS_U2 + Q_ + i] = q;
                    v += q; v2 += q * q;
                }
            }
        }
        #pragma unroll
        for (int off = 32; off > 0; off >>= 1) {
            v  += __shfl_down(v,  off, 64);
            v2 += __shfl_down(v2, off, 64);
        }
        int wv = tid >> 6;
        if ((tid & 63) == 0) { red[wv * 2] = v; red[wv * 2 + 1] = v2; }
        __syncthreads();
        if (tid == 0) {
            ws[WS_PART  + blockIdx.x] = red[0] + red[2] + red[4] + red[6];
            ws[WS_PART2 + blockIdx.x] = red[1] + red[3] + red[5] + red[7];
        }
    } else {
        // Contraction block: v[j] = sum_k beta[k]*softplus(raw_w[k][j]); c0.
        sbeta[tid] = softplusf(raw_beta[tid]);
        __syncthreads();
        int c = tid >> 6, j = tid & 63;           // wave c handles k-chunk c
        float pv = 0.f;
        for (int k = 64 * c; k < 64 * (c + 1); ++k)
            pv += sbeta[k] * softplusf(raw_w[k * Q_ + j]);   // sbeta broadcast
        vpart[c][j] = pv;
        float pc = sbeta[tid] * softplusf(raw_w0[tid]);
        #pragma unroll
        for (int mask = 1; mask < 64; mask <<= 1)
            pc += __shfl_xor(pc, mask, 64);
        if (j == 0) cred[c] = pc;
        __syncthreads();
        if (tid < Q_) {
            float vj = (vpart[0][tid] + vpart[1][tid])
                     + (vpart[2][tid] + vpart[3][tid]);
            ws[WS_V + (Q_ - 1 - tid)] = vj;       // store REVERSED: vr[e]=v[63-e]
        }
        if (tid == 0)
            ws[WS_C0] = softplusf(raw_beta0[0])
                      + ((cred[0] + cred[1]) + (cred[2] + cred[3])) + 1e-8f;
    }
}

// Kernel B: sliding 64-dot, 4 t per thread via rolling float4s from LDS.
// Block 0 prologue writes the var-init entries (only t<64 touch them, all in
// block 0). All register indices are compile-time (rule #20).
// NOTE R1 post-mortem: no in-kernel finalize — __threadfence() on gfx950 is
// an agent-scope fence (multi-XCD) -> per-block L2 writeback; 1954 blocks of
// that stalled every pipe. k_final stays a separate dispatch.
__launch_bounds__(256)
__global__ void k_main(float* __restrict__ ws) {
    __shared__ __align__(16) float su[TPB + Q_];   // 1088 floats
    __shared__ float red[4];
    int tid = threadIdx.x;
    int l = tid & 63, w = tid >> 6;

    if (blockIdx.x == 0) {
        if (tid < 64) {
            float s1 = 0.f, s2 = 0.f;
            for (int p = tid; p < NBLK_F; p += 64) {
                s1 += ws[WS_PART  + p];
                s2 += ws[WS_PART2 + p];
            }
            #pragma unroll
            for (int mask = 1; mask < 64; mask <<= 1) {
                s1 += __shfl_xor(s1, mask, 64);
                s2 += __shfl_xor(s2, mask, 64);
            }
            float n   = (float)NT;
            float var = (s2 - s1 * s1 / n) / (n - 1.f);
            ws[WS_U2 + tid] = var;                 // u2_full[0..63] = var
        }
        __syncthreads();
    }

    int t0 = blockIdx.x * TPB;
    // Stage u2_full[t0 .. t0+1087] (overshoot past the array stays inside ws;
    // garbage only feeds masked-out t).
    for (int m = tid; m < (TPB + Q_) / 4; m += 256)
        *(f32x4*)(su + 4 * m) = *(const f32x4*)(ws + WS_U2 + t0 + 4 * m);

    float c0v = ws[WS_C0];
    f32x4 vr4[16];
    #pragma unroll
    for (int m = 0; m < 16; ++m)
        vr4[m] = *(const f32x4*)(ws + WS_V + 4 * m);
    __syncthreads();

    // Thread owns t = t0 + 4*tid + {0,1,2,3}; window su[4*tid .. 4*tid+66].
    f32x4 acc; acc[0] = c0v; acc[1] = c0v; acc[2] = c0v; acc[3] = c0v;
    const float* sw = su + 4 * tid;
    f32x4 cur = *(const f32x4*)sw;
    #pragma unroll
    for (int m = 0; m < 16; ++m) {
        f32x4 nxt = *(const f32x4*)(sw + 4 * m + 4);
        #pragma unroll
        for (int d = 0; d < 4; ++d) {
            float vv = vr4[m][d];
            // acc[j] += su[4*tid + j + 4*m + d] * vr[4*m+d]; j+d from cur/nxt.
            acc[0] = fmaf(cur[d], vv, acc[0]);
            acc[1] = fmaf(d < 3 ? cur[d + 1] : nxt[d - 3], vv, acc[1]);
            acc[2] = fmaf(d < 2 ? cur[d + 2] : nxt[d - 2], vv, acc[2]);
            acc[3] = fmaf(d < 1 ? cur[d + 3] : nxt[d - 1], vv, acc[3]);
        }
        cur = nxt;
    }

    // NLL terms: u2[t] reloaded fp32 (bitwise the k_front value).
    int t = t0 + 4 * tid;
    f32x4 u4 = *(const f32x4*)(ws + WS_U2 + Q_ + t);
    float val = 0.f;
    #pragma unroll
    for (int j = 0; j < 4; ++j)
        if (t + j < NT) val += __logf(acc[j]) + u4[j] / acc[j];

    #pragma unroll
    for (int mask = 1; mask < 64; mask <<= 1)
        val += __shfl_xor(val, mask, 64);
    if (l == 0) red[w] = val;
    __syncthreads();
    if (tid == 0)
        ws[WS_OUT + blockIdx.x] = (red[0] + red[1]) + (red[2] + red[3]);
}

// Kernel C: sum the per-block NLL partials, add the constant, write out[0].
__global__ void k_final(const float* __restrict__ ws, float* __restrict__ out) {
    __shared__ float red[4];
    int tid = threadIdx.x;
    float s = 0.f;
    for (int p = tid; p < GRID_MAIN; p += 256) s += ws[WS_OUT + p];
    #pragma unroll
    for (int mask = 1; mask < 64; mask <<= 1)
        s += __shfl_xor(s, mask, 64);
    if ((tid & 63) == 0) red[tid >> 6] = s;
    __syncthreads();
    if (tid == 0)
        out[0] = 0.5f * (float)NT * 1.8378770664093453f
               + 0.5f * ((red[0] + red[1]) + (red[2] + red[3]));
}

extern "C" void kernel_launch(void* const* d_in, const int* in_sizes, int n_in,
                              void* d_out, int out_size, void* d_ws, size_t ws_size,
                              hipStream_t stream) {
    const float* r        = (const float*)d_in[0];
    const float* a0       = (const float*)d_in[1];
    const float* a1       = (const float*)d_in[2];
    const float* raw_b0   = (const float*)d_in[3];
    const float* raw_beta = (const float*)d_in[4];
    const float* raw_w0   = (const float*)d_in[5];
    const float* raw_w    = (const float*)d_in[6];
    float* out = (float*)d_out;
    float* ws  = (float*)d_ws;

    k_front<<<NBLK_F + 1, 256, 0, stream>>>(
        r, a0, a1, raw_b0, raw_beta, raw_w0, raw_w, ws);

    k_main<<<GRID_MAIN, 256, 0, stream>>>(ws);

    k_final<<<1, 256, 0, stream>>>(ws, out);
}

// Round 5
// 91.427 us; speedup vs baseline: 1.1708x; 1.1708x over previous
//
#include <hip/hip_runtime.h>
#include <math.h>

// Problem constants (reference: K=256, Q=64, T=500001 -> n = 500000)
// KEY ALGEBRA: all inputs to relu are > 0 (softplus weights, squared u2,
// nonneg var), so relu is the identity and the K=256 MLP collapses:
//   sigma2(t) = c0 + sum_e u2_full[t+e] * vr[e]
// with vr[e] = sum_k softplus(raw_beta)[k] * softplus(raw_w)[k][63-e]
//      c0    = softplus(raw_beta0) + sum_k beta[k]*softplus(raw_w0)[k] + 1e-8
// Pure fp32 (MORE accurate than the bf16 MFMA version this replaced).
#define K_ 256
#define Q_ 64
#define NT 500000
#define TPB 1024                              // t per k_main block (4 per thread)
#define NBLK_F 489                            // u2 blocks, 1024 elems each
#define GRID_MAIN 489                         // ceil(500000/1024)

// Workspace layout (float offsets):
//  [WS_C0]               c0 (see above)
//  [WS_U2 .. +500064)    u2_full fp32: [0..63] var-init, [64+i] = u2[i]
//  [WS_V  .. +64)        vr[e] (reversed collapsed weight vector)
//  [WS_PART/2 .. +512)   per-block sum(u2), sum(u2^2) partials
//  [WS_OUT .. +512)      per-block NLL partials (summed by k_final)
#define WS_C0    2
#define WS_U2    4
#define WS_V     (WS_U2 + Q_ + NT)
#define WS_PART  (WS_V + Q_)
#define WS_PART2 (WS_PART + 512)
#define WS_OUT   (WS_PART2 + 512)

typedef __attribute__((ext_vector_type(4))) float f32x4;

__device__ __forceinline__ float softplusf(float x) {
    return (x > 20.f) ? x : log1pf(__expf(x));
}

// Kernel A: blocks [0,NBLK_F) compute u2 fp32 (float4-vectorized) + per-block
// sum(u2)/sum(u2^2) partials. Block NBLK_F contracts v = W^T beta and c0.
// R4 post-mortem: the contraction was a 64-deep rolled latency chain in ONE
// block (compiled at 16 VGPR -> ~2 loads in flight -> 40+us straggler gating
// the whole dispatch). Now: thread (c,jq) does 16 INDEPENDENT f32x4 loads
// (fully unrolled, one ~900cy latency round), beta staged in LDS once.
__global__ void k_front(const float* __restrict__ r,
                        const float* __restrict__ a0p,
                        const float* __restrict__ a1p,
                        const float* __restrict__ raw_beta0,
                        const float* __restrict__ raw_beta,
                        const float* __restrict__ raw_w0,
                        const float* __restrict__ raw_w,
                        float* __restrict__ ws) {
    __shared__ float red[8];
    __shared__ float sbeta[K_];
    __shared__ f32x4 vpart[16][16];   // [k-chunk][j-quad]
    __shared__ float cred[4];
    int tid = threadIdx.x;

    if (blockIdx.x < NBLK_F) {
        int i0 = 4 * (blockIdx.x * 256 + tid);
        float a0 = a0p[0], a1 = a1p[0];
        float v = 0.f, v2 = 0.f;
        if (i0 + 7 <= NT) {                       // r valid to index NT
            f32x4 ra = *(const f32x4*)(r + i0);
            f32x4 rb = *(const f32x4*)(r + i0 + 4);
            float u0 = ra[1] - a0 - a1 * ra[0];
            float u1 = ra[2] - a0 - a1 * ra[1];
            float u2 = ra[3] - a0 - a1 * ra[2];
            float u3 = rb[0] - a0 - a1 * ra[3];
            f32x4 q; q[0] = u0*u0; q[1] = u1*u1; q[2] = u2*u2; q[3] = u3*u3;
            *(f32x4*)(ws + WS_U2 + Q_ + i0) = q;  // aligned (i0 % 4 == 0)
            v  = (q[0] + q[1]) + (q[2] + q[3]);
            v2 = (q[0]*q[0] + q[1]*q[1]) + (q[2]*q[2] + q[3]*q[3]);
        } else {
            #pragma unroll
            for (int j = 0; j < 4; ++j) {
                int i = i0 + j;
                if (i < NT) {
                    float u = r[i + 1] - a0 - a1 * r[i];
                    float q = u * u;
                    ws[WS_U2 + Q_ + i] = q;
                    v += q; v2 += q * q;
                }
            }
        }
        #pragma unroll
        for (int off = 32; off > 0; off >>= 1) {
            v  += __shfl_down(v,  off, 64);
            v2 += __shfl_down(v2, off, 64);
        }
        int wv = tid >> 6;
        if ((tid & 63) == 0) { red[wv * 2] = v; red[wv * 2 + 1] = v2; }
        __syncthreads();
        if (tid == 0) {
            ws[WS_PART  + blockIdx.x] = red[0] + red[2] + red[4] + red[6];
            ws[WS_PART2 + blockIdx.x] = red[1] + red[3] + red[5] + red[7];
        }
    } else {
        // ---- Contraction block (ILP version) ----
        sbeta[tid] = softplusf(raw_beta[tid]);    // one load+softplus/thread
        __syncthreads();
        int c = tid >> 4, jq = tid & 15;          // k-chunk of 16, j-quad
        // 16 independent vector loads, fully unrolled -> all in flight.
        f32x4 wv[16];
        #pragma unroll
        for (int kk = 0; kk < 16; ++kk)
            wv[kk] = *(const f32x4*)(raw_w + (16 * c + kk) * Q_ + 4 * jq);
        f32x4 pv; pv[0] = pv[1] = pv[2] = pv[3] = 0.f;
        #pragma unroll
        for (int kk = 0; kk < 16; ++kk) {
            float bk = sbeta[16 * c + kk];
            pv[0] = fmaf(bk, softplusf(wv[kk][0]), pv[0]);
            pv[1] = fmaf(bk, softplusf(wv[kk][1]), pv[1]);
            pv[2] = fmaf(bk, softplusf(wv[kk][2]), pv[2]);
            pv[3] = fmaf(bk, softplusf(wv[kk][3]), pv[3]);
        }
        vpart[c][jq] = pv;
        // c0 partial rides alongside.
        float pc = sbeta[tid] * softplusf(raw_w0[tid]);
        #pragma unroll
        for (int mask = 1; mask < 64; mask <<= 1)
            pc += __shfl_xor(pc, mask, 64);
        if ((tid & 63) == 0) cred[tid >> 6] = pc;
        __syncthreads();
        if (tid < Q_) {                           // j = tid
            int q = tid >> 2, d = tid & 3;
            float vj = 0.f;
            #pragma unroll
            for (int cc = 0; cc < 16; ++cc) vj += vpart[cc][q][d];
            ws[WS_V + (Q_ - 1 - tid)] = vj;       // store REVERSED: vr[e]=v[63-e]
        }
        if (tid == 0)
            ws[WS_C0] = softplusf(raw_beta0[0])
                      + ((cred[0] + cred[1]) + (cred[2] + cred[3])) + 1e-8f;
    }
}

// Kernel B: sliding 64-dot, 4 t per thread via rolling float4s from LDS.
// Block 0 prologue writes the var-init entries (only t<64 touch them, all in
// block 0). All register indices are compile-time (rule #20).
// NOTE R1 post-mortem: no in-kernel finalize — __threadfence() on gfx950 is
// an agent-scope fence (multi-XCD) -> per-block L2 writeback; 1954 blocks of
// that stalled every pipe. k_final stays a separate dispatch.
__launch_bounds__(256)
__global__ void k_main(float* __restrict__ ws) {
    __shared__ __align__(16) float su[TPB + Q_];   // 1088 floats
    __shared__ float red[4];
    int tid = threadIdx.x;
    int l = tid & 63, w = tid >> 6;

    if (blockIdx.x == 0) {
        if (tid < 64) {
            float s1 = 0.f, s2 = 0.f;
            for (int p = tid; p < NBLK_F; p += 64) {
                s1 += ws[WS_PART  + p];
                s2 += ws[WS_PART2 + p];
            }
            #pragma unroll
            for (int mask = 1; mask < 64; mask <<= 1) {
                s1 += __shfl_xor(s1, mask, 64);
                s2 += __shfl_xor(s2, mask, 64);
            }
            float n   = (float)NT;
            float var = (s2 - s1 * s1 / n) / (n - 1.f);
            ws[WS_U2 + tid] = var;                 // u2_full[0..63] = var
        }
        __syncthreads();
    }

    int t0 = blockIdx.x * TPB;
    // Stage u2_full[t0 .. t0+1087] (overshoot past the array stays inside ws;
    // garbage only feeds masked-out t).
    for (int m = tid; m < (TPB + Q_) / 4; m += 256)
        *(f32x4*)(su + 4 * m) = *(const f32x4*)(ws + WS_U2 + t0 + 4 * m);

    float c0v = ws[WS_C0];
    f32x4 vr4[16];
    #pragma unroll
    for (int m = 0; m < 16; ++m)
        vr4[m] = *(const f32x4*)(ws + WS_V + 4 * m);
    __syncthreads();

    // Thread owns t = t0 + 4*tid + {0,1,2,3}; window su[4*tid .. 4*tid+66].
    f32x4 acc; acc[0] = c0v; acc[1] = c0v; acc[2] = c0v; acc[3] = c0v;
    const float* sw = su + 4 * tid;
    f32x4 cur = *(const f32x4*)sw;
    #pragma unroll
    for (int m = 0; m < 16; ++m) {
        f32x4 nxt = *(const f32x4*)(sw + 4 * m + 4);
        #pragma unroll
        for (int d = 0; d < 4; ++d) {
            float vv = vr4[m][d];
            // acc[j] += su[4*tid + j + 4*m + d] * vr[4*m+d]; j+d from cur/nxt.
            acc[0] = fmaf(cur[d], vv, acc[0]);
            acc[1] = fmaf(d < 3 ? cur[d + 1] : nxt[d - 3], vv, acc[1]);
            acc[2] = fmaf(d < 2 ? cur[d + 2] : nxt[d - 2], vv, acc[2]);
            acc[3] = fmaf(d < 1 ? cur[d + 3] : nxt[d - 1], vv, acc[3]);
        }
        cur = nxt;
    }

    // NLL terms: u2[t] reloaded fp32 (bitwise the k_front value).
    int t = t0 + 4 * tid;
    f32x4 u4 = *(const f32x4*)(ws + WS_U2 + Q_ + t);
    float val = 0.f;
    #pragma unroll
    for (int j = 0; j < 4; ++j)
        if (t + j < NT) val += __logf(acc[j]) + u4[j] / acc[j];

    #pragma unroll
    for (int mask = 1; mask < 64; mask <<= 1)
        val += __shfl_xor(val, mask, 64);
    if (l == 0) red[w] = val;
    __syncthreads();
    if (tid == 0)
        ws[WS_OUT + blockIdx.x] = (red[0] + red[1]) + (red[2] + red[3]);
}

// Kernel C: sum the per-block NLL partials, add the constant, write out[0].
__global__ void k_final(const float* __restrict__ ws, float* __restrict__ out) {
    __shared__ float red[4];
    int tid = threadIdx.x;
    float s = 0.f;
    for (int p = tid; p < GRID_MAIN; p += 256) s += ws[WS_OUT + p];
    #pragma unroll
    for (int mask = 1; mask < 64; mask <<= 1)
        s += __shfl_xor(s, mask, 64);
    if ((tid & 63) == 0) red[tid >> 6] = s;
    __syncthreads();
    if (tid == 0)
        out[0] = 0.5f * (float)NT * 1.8378770664093453f
               + 0.5f * ((red[0] + red[1]) + (red[2] + red[3]));
}

extern "C" void kernel_launch(void* const* d_in, const int* in_sizes, int n_in,
                              void* d_out, int out_size, void* d_ws, size_t ws_size,
                              hipStream_t stream) {
    const float* r        = (const float*)d_in[0];
    const float* a0       = (const float*)d_in[1];
    const float* a1       = (const float*)d_in[2];
    const float* raw_b0   = (const float*)d_in[3];
    const float* raw_beta = (const float*)d_in[4];
    const float* raw_w0   = (const float*)d_in[5];
    const float* raw_w    = (const float*)d_in[6];
    float* out = (float*)d_out;
    float* ws  = (float*)d_ws;

    k_front<<<NBLK_F + 1, 256, 0, stream>>>(
        r, a0, a1, raw_b0, raw_beta, raw_w0, raw_w, ws);

    k_main<<<GRID_MAIN, 256, 0, stream>>>(ws);

    k_final<<<1, 256, 0, stream>>>(ws, out);
}